// Round 8
// baseline (49.726 us; speedup 1.0000x reference)
//
#include <hip/hip_runtime.h>
#include <math.h>

#define T_DIM 4096
#define F_DIM 256
#define NROWS 4096          // B*C*F = 16*1*256
#define THREADS 512
#define WAVES 8
#define CHUNK 8             // elements per thread; 512 * 8 = 4096 = T
#define LOG2E 1.4426950408889634f

typedef float v2f __attribute__((ext_vector_type(2)));

__device__ __forceinline__ float fexp2(float v) { return __builtin_amdgcn_exp2f(v); }
__device__ __forceinline__ float flog2(float v) { return __builtin_amdgcn_logf(v); }
__device__ __forceinline__ float fexp(float v)  { return fexp2(v * LOG2E); }

__host__ __device__ constexpr float cpow(float b, int e) {
    float r = 1.0f;
    for (int i = 0; i < e; ++i) r *= b;
    return r;
}

template<int N> struct PT { float v[N]; };
template<int N>
__host__ __device__ constexpr PT<N> mk_pows(float a) {
    PT<N> t{}; float p = 1.0f;
    for (int i = 0; i < N; ++i) { t.v[i] = p; p *= a; }
    return t;
}

__device__ __forceinline__ v2f shfl_up2(v2f v, int d) {
    v2f r; r.x = __shfl_up(v.x, d, 64); r.y = __shfl_up(v.y, d, 64); return r;
}
__device__ __forceinline__ v2f shfl_down2(v2f v, int d) {
    v2f r; r.x = __shfl_down(v.x, d, 64); r.y = __shfl_down(v.y, d, 64); return r;
}

// scale constants
#define S0 0.015f
#define S1 0.02f
#define S2 0.04f
#define S3 0.08f

__global__ __launch_bounds__(THREADS, 4)
void pcen_kernel(const float* __restrict__ x,
                 const float* __restrict__ log_alpha,
                 const float* __restrict__ log_delta,
                 const float* __restrict__ log_r,
                 const float* __restrict__ z_ks,
                 float* __restrict__ out)
{
#pragma clang fp contract(fast)
    const int tid  = threadIdx.x;
    const int lane = tid & 63;
    const int wid  = tid >> 6;
    const int rid  = blockIdx.x;
    const int f    = rid & (F_DIM - 1);

    __shared__ float sred[WAVES];
    __shared__ v2f sE0f[WAVES], sE1f[WAVES];   // forward-scan wave aggregates
    __shared__ v2f sE0b[WAVES], sE1b[WAVES];   // backward-scan wave aggregates

    // ---- issue all global loads FIRST (hide HBM latency under prologue) ----
    const size_t base = (size_t)rid * T_DIM + (size_t)tid * CHUNK;
    const float4* xp = (const float4*)(x + base);
    float4 xq0 = xp[0], xq1 = xp[1];

    const float v_la = log_alpha[f];
    const float v_ld = log_delta[f];
    const float v_lr = log_r[f];
    float zf[4];
    #pragma unroll
    for (int k = 0; k < 4; ++k) zf[k] = z_ks[k * F_DIM + f];

    // ---- softmax denominator over ALL K*F = 1024 z entries (block reduce, 1 barrier) ----
    float zs = fexp(z_ks[tid]) + fexp(z_ks[tid + THREADS]);
    #pragma unroll
    for (int d = 1; d < 64; d <<= 1) zs += __shfl_xor(zs, d, 64);
    if (lane == 0) sred[wid] = zs;
    __syncthreads();
    float tot = 0.0f;
    #pragma unroll
    for (int j = 0; j < WAVES; ++j) tot += sred[j];   // broadcast reads
    const float invsum = 1.0f / tot;

    float wk[4];
    #pragma unroll
    for (int k = 0; k < 4; ++k) wk[k] = fexp(zf[k]) * invsum;
    const float alpha = fexp(v_la);
    const float delta = fexp(v_ld);
    const float rr    = fexp(v_lr);
    const float dr    = fexp2(rr * flog2(delta));   // delta^r (delta > 0)
    const float nalpha = -alpha;

    float xv[CHUNK];
    xv[0]=xq0.x; xv[1]=xq0.y; xv[2]=xq0.z; xv[3]=xq0.w;
    xv[4]=xq1.x; xv[5]=xq1.y; xv[6]=xq1.z; xv[7]=xq1.w;

    // ---- compile-time coefficient tables (pairs {0,1} and {2,3}) ----
    constexpr float a0 = 1.0f - S0, a1 = 1.0f - S1, a2 = 1.0f - S2, a3 = 1.0f - S3;
    constexpr float A0 = cpow(a0, CHUNK), A1 = cpow(a1, CHUNK);           // a^8
    constexpr float A2 = cpow(a2, CHUNK), A3 = cpow(a3, CHUNK);
    constexpr float AW0 = cpow(a0, 64*CHUNK), AW1 = cpow(a1, 64*CHUNK);   // a^512
    constexpr float AW2 = cpow(a2, 64*CHUNK), AW3 = cpow(a3, 64*CHUNK);
    constexpr PT<CHUNK+1> P0 = mk_pows<CHUNK+1>(a0);   // a^i, i=0..8
    constexpr PT<CHUNK+1> P1 = mk_pows<CHUNK+1>(a1);
    constexpr PT<CHUNK+1> P2 = mk_pows<CHUNK+1>(a2);
    constexpr PT<CHUNK+1> P3 = mk_pows<CHUNK+1>(a3);
    constexpr PT<33> PA0 = mk_pows<33>(A0);            // A^d, d=0..32
    constexpr PT<33> PA1 = mk_pows<33>(A1);
    constexpr PT<33> PA2 = mk_pows<33>(A2);
    constexpr PT<33> PA3 = mk_pows<33>(A3);

    const v2f av01 = {a0, a1}, av23 = {a2, a3};
    const v2f sv01 = {S0, S1}, sv23 = {S2, S3};
    const v2f AWv01 = {AW0, AW1}, AWv23 = {AW2, AW3};
    const float lgA0 = flog2(A0), lgA1 = flog2(A1), lgA2 = flog2(A2), lgA3 = flog2(A3);
    const v2f zero = {0.0f, 0.0f};

    v2f y0[CHUNK], y1[CHUNK];   // pair {s0,s1} and pair {s2,s3}

    // ===== forward: y[n] = a*y[n-1] + s*x[n], y[0] = x[0] =====
    {
        v2f x0v = {xv[0], xv[0]};
        y0[0] = (tid == 0) ? x0v : (sv01 * x0v);
        y1[0] = (tid == 0) ? x0v : (sv23 * x0v);
    }
    #pragma unroll
    for (int i = 1; i < CHUNK; ++i) {
        v2f xi = {xv[i], xv[i]};
        y0[i] = av01 * y0[i-1] + sv01 * xi;
        y1[i] = av23 * y1[i-1] + sv23 * xi;
    }
    {
        // wave-level inclusive scan of chunk carries (both pairs interleaved)
        v2f e0 = y0[CHUNK-1], e1 = y1[CHUNK-1];
        #pragma unroll
        for (int st = 0; st < 6; ++st) {
            const int d = 1 << st;
            const v2f Ad01 = {PA0.v[d], PA1.v[d]};
            const v2f Ad23 = {PA2.v[d], PA3.v[d]};
            v2f t0 = shfl_up2(e0, d);
            v2f t1 = shfl_up2(e1, d);
            if (lane >= d) { e0 = Ad01 * t0 + e0; e1 = Ad23 * t1 + e1; }
        }
        if (lane == 63) { sE0f[wid] = e0; sE1f[wid] = e1; }
        __syncthreads();
        v2f C0 = zero, C1 = zero;
        for (int j = 0; j < wid; ++j) {
            C0 = AWv01 * C0 + sE0f[j];
            C1 = AWv23 * C1 + sE1f[j];
        }
        v2f ex0 = shfl_up2(e0, 1), ex1 = shfl_up2(e1, 1);
        v2f cp0 = (lane == 0) ? zero : ex0;
        v2f cp1 = (lane == 0) ? zero : ex1;
        const float fl = (float)lane;
        v2f pAl01 = {fexp2(fl * lgA0), fexp2(fl * lgA1)};
        v2f pAl23 = {fexp2(fl * lgA2), fexp2(fl * lgA3)};
        v2f c0 = cp0 + pAl01 * C0;
        v2f c1 = cp1 + pAl23 * C1;
        #pragma unroll
        for (int i = 0; i < CHUNK; ++i) {
            const v2f ap01 = {P0.v[i+1], P1.v[i+1]};
            const v2f ap23 = {P2.v[i+1], P3.v[i+1]};
            y0[i] = ap01 * c0 + y0[i];
            y1[i] = ap23 * c1 + y1[i];
        }
    }

    // ===== backward (in place): z[n] = a*z[n+1] + s*y[n], z[T-1] = y[T-1] =====
    y0[CHUNK-1] = (tid == THREADS-1) ? y0[CHUNK-1] : (sv01 * y0[CHUNK-1]);
    y1[CHUNK-1] = (tid == THREADS-1) ? y1[CHUNK-1] : (sv23 * y1[CHUNK-1]);
    #pragma unroll
    for (int i = CHUNK-2; i >= 0; --i) {
        y0[i] = av01 * y0[i+1] + sv01 * y0[i];
        y1[i] = av23 * y1[i+1] + sv23 * y1[i];
    }
    {
        v2f e0 = y0[0], e1 = y1[0];
        #pragma unroll
        for (int st = 0; st < 6; ++st) {
            const int d = 1 << st;
            const v2f Ad01 = {PA0.v[d], PA1.v[d]};
            const v2f Ad23 = {PA2.v[d], PA3.v[d]};
            v2f t0 = shfl_down2(e0, d);
            v2f t1 = shfl_down2(e1, d);
            if (lane < 64 - d) { e0 = Ad01 * t0 + e0; e1 = Ad23 * t1 + e1; }
        }
        if (lane == 0) { sE0b[wid] = e0; sE1b[wid] = e1; }   // distinct buffers: no guard barrier
        __syncthreads();
        v2f C0 = zero, C1 = zero;
        for (int j = WAVES-1; j > wid; --j) {
            C0 = AWv01 * C0 + sE0b[j];
            C1 = AWv23 * C1 + sE1b[j];
        }
        v2f ex0 = shfl_down2(e0, 1), ex1 = shfl_down2(e1, 1);
        v2f cn0 = (lane == 63) ? zero : ex0;
        v2f cn1 = (lane == 63) ? zero : ex1;
        const float frl = (float)(63 - lane);
        v2f pAr01 = {fexp2(frl * lgA0), fexp2(frl * lgA1)};
        v2f pAr23 = {fexp2(frl * lgA2), fexp2(frl * lgA3)};
        v2f c0 = cn0 + pAr01 * C0;
        v2f c1 = cn1 + pAr23 * C1;
        #pragma unroll
        for (int i = CHUNK-1; i >= 0; --i) {
            const v2f ap01 = {P0.v[CHUNK-i], P1.v[CHUNK-i]};
            const v2f ap23 = {P2.v[CHUNK-i], P3.v[CHUNK-i]};
            y0[i] = ap01 * c0 + y0[i];
            y1[i] = ap23 * c1 + y1[i];
        }
    }

    // ---- epilogue: M = Σ w_k y_k; M' = (M+eps)^(-alpha); out = (x*M'+delta)^r - delta^r ----
    float4* op = (float4*)(out + base);
    const v2f wv01 = {wk[0], wk[1]}, wv23 = {wk[2], wk[3]};
    #pragma unroll
    for (int j = 0; j < 2; ++j) {
        float o[4];
        #pragma unroll
        for (int q = 0; q < 4; ++q) {
            const int i = 4*j + q;
            v2f mp = wv01 * y0[i] + wv23 * y1[i];
            const float M  = mp.x + mp.y;
            const float Mp = fexp2(nalpha * flog2(M + 1.0e-6f));
            const float v  = fmaf(xv[i], Mp, delta);
            o[q] = fexp2(rr * flog2(v)) - dr;
        }
        op[j] = make_float4(o[0], o[1], o[2], o[3]);
    }
}

extern "C" void kernel_launch(void* const* d_in, const int* in_sizes, int n_in,
                              void* d_out, int out_size, void* d_ws, size_t ws_size,
                              hipStream_t stream) {
    const float* x  = (const float*)d_in[0];
    const float* la = (const float*)d_in[1];
    const float* ld = (const float*)d_in[2];
    const float* lr = (const float*)d_in[3];
    const float* zk = (const float*)d_in[4];
    float* o = (float*)d_out;
    (void)in_sizes; (void)n_in; (void)out_size; (void)d_ws; (void)ws_size;
    hipLaunchKernelGGL(pcen_kernel, dim3(NROWS), dim3(THREADS), 0, stream,
                       x, la, ld, lr, zk, o);
}

// Round 9
// 37.416 us; speedup vs baseline: 1.3290x; 1.3290x over previous
//
#include <hip/hip_runtime.h>
#include <math.h>

#define T_DIM 4096
#define F_DIM 256
#define NROWS 4096          // B*C*F = 16*1*256
#define CHUNK 16            // elements per thread; 256 threads * 16 = 4096 = T
#define LOG2E 1.4426950408889634f

typedef float v2f __attribute__((ext_vector_type(2)));

__device__ __forceinline__ float fexp2(float v) { return __builtin_amdgcn_exp2f(v); }
__device__ __forceinline__ float flog2(float v) { return __builtin_amdgcn_logf(v); }
__device__ __forceinline__ float fexp(float v)  { return fexp2(v * LOG2E); }

__host__ __device__ constexpr float cpow(float b, int e) {
    float r = 1.0f;
    for (int i = 0; i < e; ++i) r *= b;
    return r;
}

template<int N> struct PT { float v[N]; };
template<int N>
__host__ __device__ constexpr PT<N> mk_pows(float a) {
    PT<N> t{}; float p = 1.0f;
    for (int i = 0; i < N; ++i) { t.v[i] = p; p *= a; }
    return t;
}

__device__ __forceinline__ v2f shfl_up2(v2f v, int d) {
    v2f r; r.x = __shfl_up(v.x, d, 64); r.y = __shfl_up(v.y, d, 64); return r;
}
__device__ __forceinline__ v2f shfl_down2(v2f v, int d) {
    v2f r; r.x = __shfl_down(v.x, d, 64); r.y = __shfl_down(v.y, d, 64); return r;
}

// scale constants
#define S0 0.015f
#define S1 0.02f
#define S2 0.04f
#define S3 0.08f

__global__ __launch_bounds__(256, 4)
void pcen_kernel(const float* __restrict__ x,
                 const float* __restrict__ log_alpha,
                 const float* __restrict__ log_delta,
                 const float* __restrict__ log_r,
                 const float* __restrict__ z_ks,
                 float* __restrict__ out)
{
#pragma clang fp contract(fast)
    const int tid  = threadIdx.x;
    const int lane = tid & 63;
    const int wid  = tid >> 6;
    const int rid  = blockIdx.x;
    const int f    = rid & (F_DIM - 1);

    __shared__ float sred[4];
    __shared__ v2f sEf0[4], sEf1[4];   // forward wave aggregates (pairs 01, 23)
    __shared__ v2f sEb0[4], sEb1[4];   // backward wave aggregates

    // ---- issue ALL global loads first ----
    const size_t rbase = (size_t)rid * T_DIM;
    const size_t base  = rbase + (size_t)tid * CHUNK;
    const float4* xp = (const float4*)(x + base);
    float4 xq0 = xp[0], xq1 = xp[1], xq2 = xp[2], xq3 = xp[3];
    const float x0bc = x[rbase];                  // broadcast x[0] of this row
    const float v_la = log_alpha[f];
    const float v_ld = log_delta[f];
    const float v_lr = log_r[f];
    float zf[4];
    #pragma unroll
    for (int k = 0; k < 4; ++k) zf[k] = z_ks[k * F_DIM + f];

    // ---- softmax partial (per wave; cross-wave via the single barrier below) ----
    float zs = fexp(z_ks[tid])       + fexp(z_ks[tid + 256])
             + fexp(z_ks[tid + 512]) + fexp(z_ks[tid + 768]);
    #pragma unroll
    for (int d = 32; d >= 1; d >>= 1) zs += __shfl_down(zs, d, 64);
    if (lane == 0) sred[wid] = zs;

    float xv[CHUNK];
    xv[0]=xq0.x; xv[1]=xq0.y; xv[2]=xq0.z; xv[3]=xq0.w;
    xv[4]=xq1.x; xv[5]=xq1.y; xv[6]=xq1.z; xv[7]=xq1.w;
    xv[8]=xq2.x; xv[9]=xq2.y; xv[10]=xq2.z; xv[11]=xq2.w;
    xv[12]=xq3.x; xv[13]=xq3.y; xv[14]=xq3.z; xv[15]=xq3.w;

    // ---- per-f parameter chain (independent of barrier) ----
    float ez[4];
    #pragma unroll
    for (int k = 0; k < 4; ++k) ez[k] = fexp(zf[k]);
    const float alpha = fexp(v_la);
    const float delta = fexp(v_ld);
    const float rr    = fexp(v_lr);
    const float dr    = fexp2(rr * flog2(delta));   // delta^r
    const float nalpha = -alpha;

    // ---- compile-time coefficient tables ----
    constexpr float a0 = 1.0f - S0, a1 = 1.0f - S1, a2 = 1.0f - S2, a3 = 1.0f - S3;
    constexpr float A0 = cpow(a0, CHUNK), A1 = cpow(a1, CHUNK);
    constexpr float A2 = cpow(a2, CHUNK), A3 = cpow(a3, CHUNK);
    constexpr float AW0 = cpow(a0, 64*CHUNK), AW1 = cpow(a1, 64*CHUNK);
    constexpr float AW2 = cpow(a2, 64*CHUNK), AW3 = cpow(a3, 64*CHUNK);
    constexpr PT<33> PA0 = mk_pows<33>(A0);
    constexpr PT<33> PA1 = mk_pows<33>(A1);
    constexpr PT<33> PA2 = mk_pows<33>(A2);
    constexpr PT<33> PA3 = mk_pows<33>(A3);
    // c1 = s/(1-a^2), c2 = s^2/(1-a^2)
    constexpr float C1_0 = S0/(1.0f-a0*a0), C1_1 = S1/(1.0f-a1*a1);
    constexpr float C1_2 = S2/(1.0f-a2*a2), C1_3 = S3/(1.0f-a3*a3);
    constexpr float C2_0 = S0*S0/(1.0f-a0*a0), C2_1 = S1*S1/(1.0f-a1*a1);
    constexpr float C2_2 = S2*S2/(1.0f-a2*a2), C2_3 = S3*S3/(1.0f-a3*a3);

    const v2f av01 = {a0, a1}, av23 = {a2, a3};
    const v2f sv01 = {S0, S1}, sv23 = {S2, S3};
    const v2f AWv01 = {AW0, AW1}, AWv23 = {AW2, AW3};
    const float lgA0 = flog2(A0), lgA1 = flog2(A1), lgA2 = flog2(A2), lgA3 = flog2(A3);
    const v2f zero = {0.0f, 0.0f};

    // ===== Phase A: per-thread fwd & bwd aggregates (no arrays, 4 independent chains) =====
    v2f ef0, ef1, eb0, eb1;
    {
        v2f xa = {xv[0],  xv[0]};
        v2f xb = {xv[15], xv[15]};
        ef0 = sv01 * xa;  ef1 = sv23 * xa;     // forward local, zero carry-in
        eb0 = sv01 * xb;  eb1 = sv23 * xb;     // backward local, zero carry-in
        #pragma unroll
        for (int i = 1; i < CHUNK; ++i) {
            v2f xi = {xv[i],    xv[i]};
            v2f xj = {xv[15-i], xv[15-i]};
            ef0 = av01 * ef0 + sv01 * xi;
            ef1 = av23 * ef1 + sv23 * xi;
            eb0 = av01 * eb0 + sv01 * xj;
            eb1 = av23 * eb1 + sv23 * xj;
        }
    }

    // ===== Phase B: lane scans (fwd up-scan, bwd down-scan, interleaved) =====
    #pragma unroll
    for (int st = 0; st < 6; ++st) {
        const int d = 1 << st;
        const v2f Ad01 = {PA0.v[d], PA1.v[d]};
        const v2f Ad23 = {PA2.v[d], PA3.v[d]};
        v2f tf0 = shfl_up2(ef0, d);
        v2f tf1 = shfl_up2(ef1, d);
        v2f tb0 = shfl_down2(eb0, d);
        v2f tb1 = shfl_down2(eb1, d);
        if (lane >= d)      { ef0 = Ad01 * tf0 + ef0; ef1 = Ad23 * tf1 + ef1; }
        if (lane < 64 - d)  { eb0 = Ad01 * tb0 + eb0; eb1 = Ad23 * tb1 + eb1; }
    }
    // neighbor-exclusive values (register exchange, before barrier)
    v2f exf0 = shfl_up2(ef0, 1),  exf1 = shfl_up2(ef1, 1);
    v2f exb0 = shfl_down2(eb0, 1), exb1 = shfl_down2(eb1, 1);

    if (lane == 63) { sEf0[wid] = ef0; sEf1[wid] = ef1; }
    if (lane == 0)  { sEb0[wid] = eb0; sEb1[wid] = eb1; }
    __syncthreads();                         // THE single barrier

    // ---- softmax finish + folded weights ----
    const float invsum = 1.0f / (sred[0] + sred[1] + sred[2] + sred[3]);
    const float wk0 = ez[0]*invsum, wk1 = ez[1]*invsum, wk2 = ez[2]*invsum, wk3 = ez[3]*invsum;
    const v2f wf01 = {wk0*C1_0, wk1*C1_1};
    const v2f wf23 = {wk2*C1_2, wk3*C1_3};
    const float W2 = wk0*C2_0 + wk1*C2_1 + wk2*C2_2 + wk3*C2_3;

    // ---- cross-wave Horner fixups ----
    const v2f x0v = {x0bc, x0bc};
    v2f Cf0 = x0v, Cf1 = x0v;                 // fwd seed: replicate-left = x[0]
    for (int j = 0; j < wid; ++j) {
        Cf0 = AWv01 * Cf0 + sEf0[j];
        Cf1 = AWv23 * Cf1 + sEf1[j];
    }
    v2f yT0 = x0v, yT1 = x0v;                 // forward grand total y[T-1]
    #pragma unroll
    for (int j = 0; j < 4; ++j) {
        yT0 = AWv01 * yT0 + sEf0[j];
        yT1 = AWv23 * yT1 + sEf1[j];
    }
    v2f Cb0 = yT0, Cb1 = yT1;                 // bwd seed: replicate-right = y[T-1] (exact)
    for (int j = 3; j > wid; --j) {
        Cb0 = AWv01 * Cb0 + sEb0[j];
        Cb1 = AWv23 * Cb1 + sEb1[j];
    }

    // ---- per-thread incoming carries ----
    const float fl  = (float)lane;
    const float frl = (float)(63 - lane);
    v2f pAl01 = {fexp2(fl * lgA0),  fexp2(fl * lgA1)};
    v2f pAl23 = {fexp2(fl * lgA2),  fexp2(fl * lgA3)};
    v2f pAr01 = {fexp2(frl * lgA0), fexp2(frl * lgA1)};
    v2f pAr23 = {fexp2(frl * lgA2), fexp2(frl * lgA3)};
    v2f cpf0 = (lane == 0) ? zero : exf0;
    v2f cpf1 = (lane == 0) ? zero : exf1;
    v2f cnb0 = (lane == 63) ? zero : exb0;
    v2f cnb1 = (lane == 63) ? zero : exb1;
    v2f cf0 = cpf0 + pAl01 * Cf0;             // true y[base-1]
    v2f cf1 = cpf1 + pAl23 * Cf1;
    v2f cb0 = cnb0 + pAr01 * Cb0;             // true z[base+16]
    v2f cb1 = cnb1 + pAr23 * Cb1;

    // ===== Phase C: fused recompute + combine =====
    float Macc[CHUNK];
    {   // forward sweep
        v2f yf0 = cf0, yf1 = cf1;
        #pragma unroll
        for (int i = 0; i < CHUNK; ++i) {
            v2f xi = {xv[i], xv[i]};
            yf0 = av01 * yf0 + sv01 * xi;
            yf1 = av23 * yf1 + sv23 * xi;
            v2f mp = wf01 * yf0 + wf23 * yf1;
            Macc[i] = mp.x + mp.y;
        }
    }
    {   // backward sweep
        v2f zb0 = cb0, zb1 = cb1;
        #pragma unroll
        for (int i = CHUNK-1; i >= 0; --i) {
            v2f xi = {xv[i], xv[i]};
            zb0 = av01 * zb0 + sv01 * xi;
            zb1 = av23 * zb1 + sv23 * xi;
            v2f mp = wf01 * zb0 + wf23 * zb1;
            Macc[i] = Macc[i] + (mp.x + mp.y) - W2 * xv[i];
        }
    }

    // ---- epilogue: M' = (M+eps)^(-alpha); out = (x*M'+delta)^r - delta^r ----
    float4* op = (float4*)(out + base);
    #pragma unroll
    for (int j = 0; j < 4; ++j) {
        float o[4];
        #pragma unroll
        for (int q = 0; q < 4; ++q) {
            const int i = 4*j + q;
            const float Mp = fexp2(nalpha * flog2(Macc[i] + 1.0e-6f));
            const float v  = fmaf(xv[i], Mp, delta);
            o[q] = fexp2(rr * flog2(v)) - dr;
        }
        op[j] = make_float4(o[0], o[1], o[2], o[3]);
    }
}

extern "C" void kernel_launch(void* const* d_in, const int* in_sizes, int n_in,
                              void* d_out, int out_size, void* d_ws, size_t ws_size,
                              hipStream_t stream) {
    const float* x  = (const float*)d_in[0];
    const float* la = (const float*)d_in[1];
    const float* ld = (const float*)d_in[2];
    const float* lr = (const float*)d_in[3];
    const float* zk = (const float*)d_in[4];
    float* o = (float*)d_out;
    (void)in_sizes; (void)n_in; (void)out_size; (void)d_ws; (void)ws_size;
    hipLaunchKernelGGL(pcen_kernel, dim3(NROWS), dim3(256), 0, stream,
                       x, la, ld, lr, zk, o);
}